// Round 4
// baseline (1712.569 us; speedup 1.0000x reference)
//
#include <hip/hip_runtime.h>
#include <hip/hip_bf16.h>

#define NN 10000     // nodes
#define NE 100000    // edges
#define DD 64        // node_out_feats
#define EH_ 128      // edge_hidden_feats
#define NI_ 74       // node_in_feats
#define EI_ 12       // edge_in_feats
#define NSTEPS 6
#define PADN 10240
#define NODES_PB 8
#define NBLK ((NN + NODES_PB - 1) / NODES_PB)
#define STRIDE_W 4097   // u32 words per node in LDS (odd -> bank spread)

typedef short bf16x8 __attribute__((ext_vector_type(8)));
typedef float f32x4 __attribute__((ext_vector_type(4)));

static __device__ __forceinline__ unsigned short f2b(float f) {
    unsigned int u = __float_as_uint(f);
    u += 0x7fffu + ((u >> 16) & 1u);
    return (unsigned short)(u >> 16);
}

__global__ void k_zero(float* p, int n) {
    int i = blockIdx.x * blockDim.x + threadIdx.x;
    if (i < n) p[i] = 0.f;
}

// node_feats = relu(x @ W_proj^T + b_proj); hidden = node_feats. One wave per node.
__global__ void k_proj(const float* __restrict__ x, const float* __restrict__ Wp,
                       const float* __restrict__ bp, float* __restrict__ nf,
                       float* __restrict__ hid) {
    int w = (blockIdx.x * blockDim.x + threadIdx.x) >> 6;
    int lane = threadIdx.x & 63;
    if (w >= NN) return;
    const float* xr = x + (size_t)w * NI_;
    float x0 = xr[lane];
    float x1 = (lane < NI_ - 64) ? xr[64 + lane] : 0.f;
    float acc = bp[lane];
    const float* wr = Wp + (size_t)lane * NI_;
    #pragma unroll
    for (int i = 0; i < 64; i++) acc += __shfl(x0, i, 64) * wr[i];
    #pragma unroll
    for (int i = 0; i < NI_ - 64; i++) acc += __shfl(x1, i, 64) * wr[64 + i];
    acc = fmaxf(acc, 0.f);
    nf[(size_t)w * DD + lane] = acc;
    hid[(size_t)w * DD + lane] = acc;
}

__global__ void k_hist(const int* __restrict__ srcv, int* __restrict__ hist) {
    int e = blockIdx.x * blockDim.x + threadIdx.x;
    if (e < NE) atomicAdd(&hist[srcv[e]], 1);
}

// exclusive scan of hist -> rowptr[0..NN], cursor copy. Single block 1024 thr.
__global__ void k_scan(const int* __restrict__ hist, int* __restrict__ rowptr,
                       int* __restrict__ cursor) {
    __shared__ int part[1024];
    int t = threadIdx.x;
    const int PER = (NN + 1023) / 1024;
    int b0 = t * PER;
    int sum = 0;
    for (int i = 0; i < PER; i++) { int b = b0 + i; if (b < NN) sum += hist[b]; }
    part[t] = sum;
    __syncthreads();
    for (int off = 1; off < 1024; off <<= 1) {
        int v = (t >= off) ? part[t - off] : 0;
        __syncthreads();
        part[t] += v;
        __syncthreads();
    }
    int run = (t > 0) ? part[t - 1] : 0;
    for (int i = 0; i <= PER; i++) {
        int b = b0 + i;
        if (b <= NN) {
            rowptr[b] = run;
            if (b < NN) cursor[b] = run;
        }
        if (b < NN && i < PER) run += hist[b];
        if (i == PER) break;
    }
}

__global__ void k_scatter(const int* __restrict__ srcv, const int* __restrict__ dstv,
                          int* __restrict__ cursor, int* __restrict__ perm,
                          int* __restrict__ dsts_s) {
    int e = blockIdx.x * blockDim.x + threadIdx.x;
    if (e >= NE) return;
    int s = srcv[e];
    int pos = atomicAdd(&cursor[s], 1);
    perm[pos] = e;
    dsts_s[pos] = dstv[e];
}

// eh (sorted order) = relu(edge_attr[perm[p]] @ W_e1^T + b_e1).
__global__ void k_eh_s(const float* __restrict__ ea, const float* __restrict__ W1,
                       const float* __restrict__ b1, const int* __restrict__ perm,
                       float* __restrict__ ehs) {
    __shared__ float s_ea[2][EI_];
    __shared__ float s_W[EH_ * EI_];
    int t = threadIdx.x;
    for (int i = t; i < EH_ * EI_; i += 256) s_W[i] = W1[i];
    int p0 = blockIdx.x * 2;
    if (t < 2 * EI_) {
        int pp = p0 + t / EI_;
        int ee = (pp < NE) ? perm[pp] : 0;
        s_ea[t / EI_][t % EI_] = (pp < NE) ? ea[(size_t)ee * EI_ + t % EI_] : 0.f;
    }
    __syncthreads();
    int le = t >> 7;
    int h = t & 127;
    int p = p0 + le;
    if (p >= NE) return;
    float acc = b1[h];
    #pragma unroll
    for (int i = 0; i < EI_; i++) acc += s_ea[le][i] * s_W[h * EI_ + i];
    ehs[(size_t)p * EH_ + h] = fmaxf(acc, 0.f);
}

// Pack W_e2 into bf16 MFMA fragment order (serves as A-frags of swapped GEMM).
// Bpk[(((ct*2+t)*4+g)*16+n)*8+j] = bf16(B[d][c]), d=t*32+g*8+j, c=ct*16+n,
// B[d][h*64+f] = W_e2[(d*64+f)*128+h].
__global__ void k_pB(const float* __restrict__ W2, unsigned short* __restrict__ Bpk) {
    int idx = blockIdx.x * 256 + threadIdx.x;
    if (idx >= DD * EH_ * DD) return;
    int j = idx & 7;
    int n = (idx >> 3) & 15;
    int gg = idx >> 7;
    int g = gg & 3;
    int tt = gg >> 2;
    int t = tt & 1;
    int ct = tt >> 1;
    int d = t * 32 + g * 8 + j;
    int c = ct * 16 + n;
    int h = c >> 6, f = c & 63;
    Bpk[idx] = f2b(W2[((size_t)(d * 64 + f)) * EH_ + h]);
}

__global__ void k_tG(const float* __restrict__ W, float* __restrict__ Wt) {
    int idx = blockIdx.x * 256 + threadIdx.x;
    if (idx >= 192 * 64) return;
    int j = idx / 64, d2 = idx % 64;
    Wt[d2 * 192 + j] = W[idx];
}

__global__ void k_cnt(const int* __restrict__ dstv, float* __restrict__ cnt) {
    int e = blockIdx.x * blockDim.x + threadIdx.x;
    if (e < NE) atomicAdd(&cnt[dstv[e]], 1.0f);
}

// xp = nf @ W_lin^T + b_lin (-> bf16 xpb); btp = xp @ reshape(b_e2,64,64); agg = 0.
// Covers PADN+16 rows; pad rows get zeros in xpb.
__global__ void k_xp(const float* __restrict__ nf, const float* __restrict__ Wl,
                     const float* __restrict__ bl, const float* __restrict__ be2,
                     unsigned short* __restrict__ xpb, float* __restrict__ btp,
                     float* __restrict__ agg) {
    int w = (blockIdx.x * blockDim.x + threadIdx.x) >> 6;
    int lane = threadIdx.x & 63;
    if (w >= PADN + 16) return;
    if (w >= NN) { xpb[(size_t)w * DD + lane] = 0; return; }
    float nv = nf[(size_t)w * DD + lane];
    float acc = bl[lane];
    const float* wr = Wl + (size_t)lane * DD;
    #pragma unroll
    for (int d = 0; d < DD; d++) acc += __shfl(nv, d, 64) * wr[d];
    xpb[(size_t)w * DD + lane] = f2b(acc);
    float bt = 0.f;
    #pragma unroll
    for (int d = 0; d < DD; d++) bt += __shfl(acc, d, 64) * be2[d * DD + lane];
    btp[(size_t)w * DD + lane] = bt;
    agg[(size_t)w * DD + lane] = 0.f;
}

// Fused: per block of 8 nodes, compute V rows (8 x 8192) via MFMA into LDS,
// then apply this block's edges from LDS. Swapped operands: D[c,node],
// lane holds node = lane&15 (only n<8 stored), c rows = (lane>>4)*4+rg.
__global__ __launch_bounds__(1024, 1) void k_fused(
        const unsigned short* __restrict__ xpb,
        const unsigned short* __restrict__ Bpk,
        const int* __restrict__ rowptr, const int* __restrict__ dsts,
        const float* __restrict__ ehs, const float* __restrict__ btp,
        float* __restrict__ agg) {
    __shared__ unsigned int Vlds[NODES_PB * STRIDE_W];   // 131104 B
    int tid = threadIdx.x;
    int w = tid >> 6, lane = tid & 63;
    int g = lane >> 4, n = lane & 15;
    int nb = blockIdx.x * NODES_PB;
    // B-frag: xp^T for the block's node columns
    const unsigned short* xr = xpb + (size_t)(nb + n) * DD + g * 8;
    bf16x8 xb0 = *(const bf16x8*)xr;
    bf16x8 xb1 = *(const bf16x8*)(xr + 32);
    // GEMM: wave w handles c-tiles ct in [w*32, w*32+32)
    int ct0 = w * 32;
    unsigned short* sp = (unsigned short*)Vlds;
    #pragma unroll 4
    for (int i = 0; i < 32; i++) {
        int ct = ct0 + i;
        const unsigned short* ap = Bpk + (size_t)(ct * 8 + g) * 128 + n * 8;
        bf16x8 a0 = *(const bf16x8*)ap;
        bf16x8 a1 = *(const bf16x8*)(ap + 512);   // t=1 fragment
        f32x4 acc = {0.f, 0.f, 0.f, 0.f};
        acc = __builtin_amdgcn_mfma_f32_16x16x32_bf16(a0, xb0, acc, 0, 0, 0);
        acc = __builtin_amdgcn_mfma_f32_16x16x32_bf16(a1, xb1, acc, 0, 0, 0);
        if (n < NODES_PB) {
            int h = ct >> 2;                       // 16 | 64 -> uniform per tile
            int word0 = n * STRIDE_W + (h >> 1) * 64 + (ct & 3) * 16 + g * 4;
            int hs = h & 1;
            #pragma unroll
            for (int rg = 0; rg < 4; rg++)
                sp[(size_t)(word0 + rg) * 2 + hs] = f2b(acc[rg]);
        }
    }
    __syncthreads();
    // edge phase: wave pair (w>>1) -> node; odd/even waves take alternating groups
    int s = nb + (w >> 1);
    if (s >= NN) return;
    int r0 = __builtin_amdgcn_readfirstlane(rowptr[s]);
    int r1 = __builtin_amdgcn_readfirstlane(rowptr[s + 1]);
    if (r0 == r1) return;
    const unsigned int* Vl = Vlds + (size_t)(w >> 1) * STRIDE_W;
    float btv = btp[(size_t)s * DD + lane];
    for (int base = r0 + (w & 1) * 8; base < r1; base += 16) {
        int m = r1 - base; if (m > 8) m = 8;
        const float* ehp = ehs + (size_t)base * EH_;
        float a8[8] = {0.f, 0.f, 0.f, 0.f, 0.f, 0.f, 0.f, 0.f};
        #pragma unroll 4
        for (int hh = 0; hh < 64; hh++) {
            unsigned int v = Vl[hh * 64 + lane];
            float f0 = __uint_as_float(v << 16);
            float f1 = __uint_as_float(v & 0xffff0000u);
            #pragma unroll
            for (int i2 = 0; i2 < 8; i2++) {
                a8[i2] = fmaf(ehp[i2 * EH_ + 2 * hh], f0, a8[i2]);
                a8[i2] = fmaf(ehp[i2 * EH_ + 2 * hh + 1], f1, a8[i2]);
            }
        }
        #pragma unroll
        for (int i2 = 0; i2 < 8; i2++) {
            if (i2 < m) {
                int dn = dsts[base + i2];
                atomicAdd(&agg[(size_t)dn * DD + lane], a8[i2] + btv);
            }
        }
    }
}

// nf = relu(agg/max(cnt,1)); GRU(nf, hidden) -> out. One wave per node.
__global__ void k_gru(const float* __restrict__ agg, const float* __restrict__ cnt,
                      const float* __restrict__ hid,
                      const float* __restrict__ WihT, const float* __restrict__ WhhT,
                      const float* __restrict__ bih, const float* __restrict__ bhh,
                      float* __restrict__ out_nf) {
    int w = (blockIdx.x * blockDim.x + threadIdx.x) >> 6;
    int lane = threadIdx.x & 63;
    if (w >= NN) return;
    float c = fmaxf(cnt[w], 1.f);
    float nfv = fmaxf(agg[(size_t)w * DD + lane] / c, 0.f);
    float hv = hid[(size_t)w * DD + lane];
    float gr = bih[lane], gz = bih[64 + lane], gn = bih[128 + lane];
    float hr = bhh[lane], hz = bhh[64 + lane], hn = bhh[128 + lane];
    for (int d = 0; d < DD; d++) {
        float nd = __shfl(nfv, d, 64);
        float hd = __shfl(hv, d, 64);
        const float* wi = WihT + d * 192;
        const float* wh = WhhT + d * 192;
        gr += nd * wi[lane];
        gz += nd * wi[64 + lane];
        gn += nd * wi[128 + lane];
        hr += hd * wh[lane];
        hz += hd * wh[64 + lane];
        hn += hd * wh[128 + lane];
    }
    float r = 1.f / (1.f + __expf(-(gr + hr)));
    float z = 1.f / (1.f + __expf(-(gz + hz)));
    float n = tanhf(gn + r * hn);
    out_nf[(size_t)w * DD + lane] = (1.f - z) * n + z * hv;
}

extern "C" void kernel_launch(void* const* d_in, const int* in_sizes, int n_in,
                              void* d_out, int out_size, void* d_ws, size_t ws_size,
                              hipStream_t stream) {
    const float* x   = (const float*)d_in[0];
    const int*   ei  = (const int*)d_in[1];
    const float* ea  = (const float*)d_in[2];
    const float* Wp  = (const float*)d_in[3];
    const float* bp  = (const float*)d_in[4];
    const float* W1  = (const float*)d_in[5];
    const float* b1  = (const float*)d_in[6];
    const float* W2  = (const float*)d_in[7];
    const float* b2  = (const float*)d_in[8];
    const float* Wl  = (const float*)d_in[9];
    const float* bl  = (const float*)d_in[10];
    const float* Wih = (const float*)d_in[11];
    const float* Whh = (const float*)d_in[12];
    const float* bih = (const float*)d_in[13];
    const float* bhh = (const float*)d_in[14];
    const int* srcv = ei;
    const int* dstv = ei + NE;

    float* p = (float*)d_ws;
    size_t off = 0;
    auto alloc = [&](size_t n) { n = (n + 3) & ~(size_t)3; float* q = p + off; off += n; return q; };
    float* nf   = alloc((size_t)NN * DD);
    float* hid  = alloc((size_t)NN * DD);
    float* btp  = alloc((size_t)NN * DD);
    float* agg  = alloc((size_t)NN * DD);
    float* cnt  = alloc(NN);
    float* ehs  = alloc((size_t)(NE + 8) * EH_);
    float* WihT = alloc(192 * 64);
    float* WhhT = alloc(192 * 64);
    int* hist   = (int*)alloc(NN);
    int* rowptr = (int*)alloc(NN + 1);
    int* cursor = (int*)alloc(NN);
    int* perm   = (int*)alloc(NE);
    int* dsts_s = (int*)alloc(NE);
    unsigned short* Bpk = (unsigned short*)alloc((size_t)DD * EH_ * DD / 2);   // bf16
    unsigned short* xpb = (unsigned short*)alloc((size_t)(PADN + 16) * DD / 2); // bf16

    // ---- one-time preprocessing ----
    k_zero<<<(NN + 255) / 256, 256, 0, stream>>>(cnt, NN);
    k_zero<<<(NN + 255) / 256, 256, 0, stream>>>((float*)hist, NN);
    k_proj<<<(NN + 3) / 4, 256, 0, stream>>>(x, Wp, bp, nf, hid);
    k_pB<<<(DD * EH_ * DD + 255) / 256, 256, 0, stream>>>(W2, Bpk);
    k_tG<<<48, 256, 0, stream>>>(Wih, WihT);
    k_tG<<<48, 256, 0, stream>>>(Whh, WhhT);
    k_cnt<<<(NE + 255) / 256, 256, 0, stream>>>(dstv, cnt);
    k_hist<<<(NE + 255) / 256, 256, 0, stream>>>(srcv, hist);
    k_scan<<<1, 1024, 0, stream>>>(hist, rowptr, cursor);
    k_scatter<<<(NE + 255) / 256, 256, 0, stream>>>(srcv, dstv, cursor, perm, dsts_s);
    k_eh_s<<<(NE + 1) / 2, 256, 0, stream>>>(ea, W1, b1, perm, ehs);

    const int xp_waves = PADN + 16;
    for (int s = 0; s < NSTEPS; s++) {
        k_xp<<<(xp_waves + 3) / 4, 256, 0, stream>>>(nf, Wl, bl, b2, xpb, btp, agg);
        k_fused<<<NBLK, 1024, 0, stream>>>(xpb, Bpk, rowptr, dsts_s, ehs, btp, agg);
        float* dest = (s == NSTEPS - 1) ? (float*)d_out : nf;
        k_gru<<<(NN + 3) / 4, 256, 0, stream>>>(agg, cnt, hid, WihT, WhhT, bih, bhh, dest);
    }
}

// Round 5
// 1071.839 us; speedup vs baseline: 1.5978x; 1.5978x over previous
//
#include <hip/hip_runtime.h>
#include <hip/hip_bf16.h>

#define NN 10000     // nodes
#define NE 100000    // edges
#define DD 64        // node_out_feats
#define EH_ 128      // edge_hidden_feats
#define NI_ 74       // node_in_feats
#define EI_ 12       // edge_in_feats
#define NSTEPS 6
#define PADN 10240

typedef short bf16x8 __attribute__((ext_vector_type(8)));
typedef float f32x4 __attribute__((ext_vector_type(4)));

static __device__ __forceinline__ unsigned short f2b(float f) {
    unsigned int u = __float_as_uint(f);
    u += 0x7fffu + ((u >> 16) & 1u);
    return (unsigned short)(u >> 16);
}

__global__ void k_zero(float* p, int n) {
    int i = blockIdx.x * blockDim.x + threadIdx.x;
    if (i < n) p[i] = 0.f;
}

// node_feats = relu(x @ W_proj^T + b_proj); hidden = node_feats. One wave per node.
__global__ void k_proj(const float* __restrict__ x, const float* __restrict__ Wp,
                       const float* __restrict__ bp, float* __restrict__ nf,
                       float* __restrict__ hid) {
    int w = (blockIdx.x * blockDim.x + threadIdx.x) >> 6;
    int lane = threadIdx.x & 63;
    if (w >= NN) return;
    const float* xr = x + (size_t)w * NI_;
    float x0 = xr[lane];
    float x1 = (lane < NI_ - 64) ? xr[64 + lane] : 0.f;
    float acc = bp[lane];
    const float* wr = Wp + (size_t)lane * NI_;
    #pragma unroll
    for (int i = 0; i < 64; i++) acc += __shfl(x0, i, 64) * wr[i];
    #pragma unroll
    for (int i = 0; i < NI_ - 64; i++) acc += __shfl(x1, i, 64) * wr[64 + i];
    acc = fmaxf(acc, 0.f);
    nf[(size_t)w * DD + lane] = acc;
    hid[(size_t)w * DD + lane] = acc;
}

__global__ void k_hist(const int* __restrict__ srcv, int* __restrict__ hist) {
    int e = blockIdx.x * blockDim.x + threadIdx.x;
    if (e < NE) atomicAdd(&hist[srcv[e]], 1);
}

// exclusive scan of hist -> rowptr[0..NN], cursor copy. Single block 1024 thr.
__global__ void k_scan(const int* __restrict__ hist, int* __restrict__ rowptr,
                       int* __restrict__ cursor) {
    __shared__ int part[1024];
    int t = threadIdx.x;
    const int PER = (NN + 1023) / 1024;
    int b0 = t * PER;
    int sum = 0;
    for (int i = 0; i < PER; i++) { int b = b0 + i; if (b < NN) sum += hist[b]; }
    part[t] = sum;
    __syncthreads();
    for (int off = 1; off < 1024; off <<= 1) {
        int v = (t >= off) ? part[t - off] : 0;
        __syncthreads();
        part[t] += v;
        __syncthreads();
    }
    int run = (t > 0) ? part[t - 1] : 0;
    for (int i = 0; i <= PER; i++) {
        int b = b0 + i;
        if (b <= NN) {
            rowptr[b] = run;
            if (b < NN) cursor[b] = run;
        }
        if (b < NN && i < PER) run += hist[b];
        if (i == PER) break;
    }
}

__global__ void k_scatter(const int* __restrict__ srcv, const int* __restrict__ dstv,
                          int* __restrict__ cursor, int* __restrict__ perm,
                          int* __restrict__ dsts_s) {
    int e = blockIdx.x * blockDim.x + threadIdx.x;
    if (e >= NE) return;
    int s = srcv[e];
    int pos = atomicAdd(&cursor[s], 1);
    perm[pos] = e;
    dsts_s[pos] = dstv[e];
}

// eh (sorted order, bf16) = relu(edge_attr[perm[p]] @ W_e1^T + b_e1).
__global__ void k_eh_s(const float* __restrict__ ea, const float* __restrict__ W1,
                       const float* __restrict__ b1, const int* __restrict__ perm,
                       unsigned short* __restrict__ ehs) {
    __shared__ float s_ea[2][EI_];
    __shared__ float s_W[EH_ * EI_];
    int t = threadIdx.x;
    for (int i = t; i < EH_ * EI_; i += 256) s_W[i] = W1[i];
    int p0 = blockIdx.x * 2;
    if (t < 2 * EI_) {
        int pp = p0 + t / EI_;
        int ee = (pp < NE) ? perm[pp] : 0;
        s_ea[t / EI_][t % EI_] = (pp < NE) ? ea[(size_t)ee * EI_ + t % EI_] : 0.f;
    }
    __syncthreads();
    int le = t >> 7;
    int h = t & 127;
    int p = p0 + le;
    if (p >= NE) return;
    float acc = b1[h];
    #pragma unroll
    for (int i = 0; i < EI_; i++) acc += s_ea[le][i] * s_W[h * EI_ + i];
    ehs[(size_t)p * EH_ + h] = f2b(fmaxf(acc, 0.f));
}

// Pack W_e2 into bf16 MFMA B-fragment order.
// Bpk[(((ct*2+t)*4+g)*16+n)*8+j] = bf16(B[d][c]), d=t*32+g*8+j, c=ct*16+n,
// B[d][h*64+f] = W_e2[(d*64+f)*128+h].
__global__ void k_pB(const float* __restrict__ W2, unsigned short* __restrict__ Bpk) {
    int idx = blockIdx.x * 256 + threadIdx.x;
    if (idx >= DD * EH_ * DD) return;
    int j = idx & 7;
    int n = (idx >> 3) & 15;
    int gg = idx >> 7;
    int g = gg & 3;
    int tt = gg >> 2;
    int t = tt & 1;
    int ct = tt >> 1;
    int d = t * 32 + g * 8 + j;
    int c = ct * 16 + n;
    int h = c >> 6, f = c & 63;
    Bpk[idx] = f2b(W2[((size_t)(d * 64 + f)) * EH_ + h]);
}

__global__ void k_tG(const float* __restrict__ W, float* __restrict__ Wt) {
    int idx = blockIdx.x * 256 + threadIdx.x;
    if (idx >= 192 * 64) return;
    int j = idx / 64, d2 = idx % 64;
    Wt[d2 * 192 + j] = W[idx];
}

__global__ void k_cnt(const int* __restrict__ dstv, float* __restrict__ cnt) {
    int e = blockIdx.x * blockDim.x + threadIdx.x;
    if (e < NE) atomicAdd(&cnt[dstv[e]], 1.0f);
}

// xp = nf @ W_lin^T + b_lin (-> bf16 xpb); btp = xp @ reshape(b_e2,64,64); agg = 0.
__global__ void k_xp(const float* __restrict__ nf, const float* __restrict__ Wl,
                     const float* __restrict__ bl, const float* __restrict__ be2,
                     unsigned short* __restrict__ xpb, float* __restrict__ btp,
                     float* __restrict__ agg) {
    int w = (blockIdx.x * blockDim.x + threadIdx.x) >> 6;
    int lane = threadIdx.x & 63;
    if (w >= NN) return;
    float nv = nf[(size_t)w * DD + lane];
    float acc = bl[lane];
    const float* wr = Wl + (size_t)lane * DD;
    #pragma unroll
    for (int d = 0; d < DD; d++) acc += __shfl(nv, d, 64) * wr[d];
    xpb[(size_t)w * DD + lane] = f2b(acc);
    float bt = 0.f;
    #pragma unroll
    for (int d = 0; d < DD; d++) bt += __shfl(acc, d, 64) * be2[d * DD + lane];
    btp[(size_t)w * DD + lane] = bt;
    agg[(size_t)w * DD + lane] = 0.f;
}

// MFMA GEMM: V[l, c] = sum_d xpb[c0+l, d] * B[d, c], bf16 h-paired layout
// (c = h*64+f at cp = (h>>1)*128 + f*2 + (h&1)).
// grid: (chnp/256, 64); block 256 (4 waves). Block: 256 rows x 128 c (one h-pair).
// Epilogue: stage slab in wave-private LDS, store 256B-contiguous rows (b128).
__global__ void k_V(const unsigned short* __restrict__ xpb,
                    const unsigned short* __restrict__ Bpk,
                    unsigned short* __restrict__ Vb, int c0) {
    __shared__ unsigned short sb[4][16 * 136];
    int hp = blockIdx.y;            // h-pair index 0..63
    int w = threadIdx.x >> 6;
    int lane = threadIdx.x & 63;
    int g = lane >> 4, n = lane & 15;
    // B-fragments for the 8 c-tiles of this h-pair (held across whole kernel)
    bf16x8 B0[8], B1[8];
    #pragma unroll
    for (int ct8 = 0; ct8 < 8; ct8++) {
        int ctg = hp * 8 + ct8;
        const unsigned short* bp = Bpk + (size_t)(ctg * 8 + g) * 128 + n * 8;
        B0[ct8] = *(const bf16x8*)bp;
        B1[ct8] = *(const bf16x8*)(bp + 512);
    }
    int r0 = blockIdx.x * 256 + w * 64;
    unsigned short* sw = sb[w];
    #pragma unroll
    for (int mt = 0; mt < 4; mt++) {
        int row = r0 + mt * 16 + n;
        const unsigned short* ap = xpb + ((size_t)(c0 + row)) * DD + g * 8;
        bf16x8 a0 = *(const bf16x8*)ap;
        bf16x8 a1 = *(const bf16x8*)(ap + 32);
        #pragma unroll
        for (int ct8 = 0; ct8 < 8; ct8++) {
            f32x4 acc = {0.f, 0.f, 0.f, 0.f};
            acc = __builtin_amdgcn_mfma_f32_16x16x32_bf16(a0, B0[ct8], acc, 0, 0, 0);
            acc = __builtin_amdgcn_mfma_f32_16x16x32_bf16(a1, B1[ct8], acc, 0, 0, 0);
            int cl = ct8 * 16 + n;                       // local col 0..127
            int cpl = ((cl & 63) << 1) | (cl >> 6);      // h-paired local offset
            #pragma unroll
            for (int rg = 0; rg < 4; rg++)
                sw[(g * 4 + rg) * 136 + cpl] = f2b(acc[rg]);
        }
        // wave-synchronous readback + coalesced store: 4 rows x 256B per op
        #pragma unroll
        for (int q = 0; q < 4; q++) {
            int lr = (lane >> 4) + q * 4;   // staging row 0..15
            int ch = lane & 15;             // 16B chunk 0..15
            bf16x8 v = *(const bf16x8*)&sw[lr * 136 + ch * 8];
            *(bf16x8*)(Vb + (size_t)(r0 + mt * 16 + lr) * 8192 + hp * 128 + ch * 8) = v;
        }
    }
}

// Grouped-by-src edge kernel, bf16 V (h-paired) + bf16 eh. One wave per node.
__global__ void k_edge_g(const int* __restrict__ rowptr, const int* __restrict__ dsts,
                         const unsigned short* __restrict__ ehs,
                         const unsigned short* __restrict__ Vb,
                         const float* __restrict__ btp, float* __restrict__ agg,
                         int c0, int c1) {
    int w = (blockIdx.x * blockDim.x + threadIdx.x) >> 6;
    int lane = threadIdx.x & 63;
    int s = c0 + w;
    if (s >= c1) return;
    int r0 = __builtin_amdgcn_readfirstlane(rowptr[s]);
    int r1 = __builtin_amdgcn_readfirstlane(rowptr[s + 1]);
    if (r0 == r1) return;
    const unsigned int* Vrow = (const unsigned int*)(Vb + (size_t)(s - c0) * 8192) + lane;
    float btv = btp[(size_t)s * DD + lane];
    for (int base = r0; base < r1; base += 8) {
        int m = r1 - base; if (m > 8) m = 8;
        const unsigned int* ehp = (const unsigned int*)(ehs + (size_t)base * EH_);
        float acc[8] = {0.f, 0.f, 0.f, 0.f, 0.f, 0.f, 0.f, 0.f};
        #pragma unroll 4
        for (int hh = 0; hh < 64; hh++) {
            unsigned int v = Vrow[(size_t)hh * 64];
            float f0 = __uint_as_float(v << 16);
            float f1 = __uint_as_float(v & 0xffff0000u);
            #pragma unroll
            for (int i = 0; i < 8; i++) {
                unsigned int ev = ehp[i * 64 + hh];
                acc[i] = fmaf(__uint_as_float(ev << 16), f0, acc[i]);
                acc[i] = fmaf(__uint_as_float(ev & 0xffff0000u), f1, acc[i]);
            }
        }
        #pragma unroll
        for (int i = 0; i < 8; i++) {
            if (i < m) {
                int dn = dsts[base + i];
                atomicAdd(&agg[(size_t)dn * DD + lane], acc[i] + btv);
            }
        }
    }
}

// nf = relu(agg/max(cnt,1)); GRU(nf, hidden) -> out. One wave per node.
__global__ void k_gru(const float* __restrict__ agg, const float* __restrict__ cnt,
                      const float* __restrict__ hid,
                      const float* __restrict__ WihT, const float* __restrict__ WhhT,
                      const float* __restrict__ bih, const float* __restrict__ bhh,
                      float* __restrict__ out_nf) {
    int w = (blockIdx.x * blockDim.x + threadIdx.x) >> 6;
    int lane = threadIdx.x & 63;
    if (w >= NN) return;
    float c = fmaxf(cnt[w], 1.f);
    float nfv = fmaxf(agg[(size_t)w * DD + lane] / c, 0.f);
    float hv = hid[(size_t)w * DD + lane];
    float gr = bih[lane], gz = bih[64 + lane], gn = bih[128 + lane];
    float hr = bhh[lane], hz = bhh[64 + lane], hn = bhh[128 + lane];
    for (int d = 0; d < DD; d++) {
        float nd = __shfl(nfv, d, 64);
        float hd = __shfl(hv, d, 64);
        const float* wi = WihT + d * 192;
        const float* wh = WhhT + d * 192;
        gr += nd * wi[lane];
        gz += nd * wi[64 + lane];
        gn += nd * wi[128 + lane];
        hr += hd * wh[lane];
        hz += hd * wh[64 + lane];
        hn += hd * wh[128 + lane];
    }
    float r = 1.f / (1.f + __expf(-(gr + hr)));
    float z = 1.f / (1.f + __expf(-(gz + hz)));
    float n = tanhf(gn + r * hn);
    out_nf[(size_t)w * DD + lane] = (1.f - z) * n + z * hv;
}

extern "C" void kernel_launch(void* const* d_in, const int* in_sizes, int n_in,
                              void* d_out, int out_size, void* d_ws, size_t ws_size,
                              hipStream_t stream) {
    const float* x   = (const float*)d_in[0];
    const int*   ei  = (const int*)d_in[1];
    const float* ea  = (const float*)d_in[2];
    const float* Wp  = (const float*)d_in[3];
    const float* bp  = (const float*)d_in[4];
    const float* W1  = (const float*)d_in[5];
    const float* b1  = (const float*)d_in[6];
    const float* W2  = (const float*)d_in[7];
    const float* b2  = (const float*)d_in[8];
    const float* Wl  = (const float*)d_in[9];
    const float* bl  = (const float*)d_in[10];
    const float* Wih = (const float*)d_in[11];
    const float* Whh = (const float*)d_in[12];
    const float* bih = (const float*)d_in[13];
    const float* bhh = (const float*)d_in[14];
    const int* srcv = ei;
    const int* dstv = ei + NE;

    float* p = (float*)d_ws;
    size_t off = 0;
    auto alloc = [&](size_t n) { n = (n + 3) & ~(size_t)3; float* q = p + off; off += n; return q; };
    float* nf   = alloc((size_t)NN * DD);
    float* hid  = alloc((size_t)NN * DD);
    float* btp  = alloc((size_t)NN * DD);
    float* agg  = alloc((size_t)NN * DD);
    float* cnt  = alloc(NN);
    unsigned short* ehs = (unsigned short*)alloc((size_t)(NE + 8) * EH_ / 2);  // bf16
    float* WihT = alloc(192 * 64);
    float* WhhT = alloc(192 * 64);
    int* hist   = (int*)alloc(NN);
    int* rowptr = (int*)alloc(NN + 1);
    int* cursor = (int*)alloc(NN);
    int* perm   = (int*)alloc(NE);
    int* dsts_s = (int*)alloc(NE);
    unsigned short* Bpk = (unsigned short*)alloc((size_t)DD * EH_ * DD / 2);   // bf16
    unsigned short* xpb = (unsigned short*)alloc((size_t)PADN * DD / 2);       // bf16

    size_t used = off;
    size_t availf = (ws_size / 4 > used) ? (ws_size / 4 - used) : 0;
    long long rows_cap = (long long)(availf / 4096);
    int CH = (int)((rows_cap / 256) * 256);
    if (CH > PADN) CH = PADN;
    if (CH < 256) CH = 256;   // assumes ws >= ~80 MB
    unsigned short* Vb = (unsigned short*)alloc((size_t)CH * 8192 / 2);        // bf16

    // ---- one-time preprocessing ----
    k_zero<<<(NN + 255) / 256, 256, 0, stream>>>(cnt, NN);
    k_zero<<<(NN + 255) / 256, 256, 0, stream>>>((float*)hist, NN);
    k_proj<<<(NN + 3) / 4, 256, 0, stream>>>(x, Wp, bp, nf, hid);
    k_pB<<<(DD * EH_ * DD + 255) / 256, 256, 0, stream>>>(W2, Bpk);
    k_tG<<<48, 256, 0, stream>>>(Wih, WihT);
    k_tG<<<48, 256, 0, stream>>>(Whh, WhhT);
    k_cnt<<<(NE + 255) / 256, 256, 0, stream>>>(dstv, cnt);
    k_hist<<<(NE + 255) / 256, 256, 0, stream>>>(srcv, hist);
    k_scan<<<1, 1024, 0, stream>>>(hist, rowptr, cursor);
    k_scatter<<<(NE + 255) / 256, 256, 0, stream>>>(srcv, dstv, cursor, perm, dsts_s);
    k_eh_s<<<(NE + 1) / 2, 256, 0, stream>>>(ea, W1, b1, perm, ehs);

    int nc = (PADN + CH - 1) / CH;
    for (int s = 0; s < NSTEPS; s++) {
        k_xp<<<(NN + 3) / 4, 256, 0, stream>>>(nf, Wl, bl, b2, xpb, btp, agg);
        for (int c = 0; c < nc; c++) {
            int c0 = c * CH;
            int chnp = (c0 + CH < PADN) ? CH : (PADN - c0);
            dim3 g(chnp / 256, 64);
            k_V<<<g, 256, 0, stream>>>(xpb, Bpk, Vb, c0);
            int c1e = (c0 + CH < NN) ? (c0 + CH) : NN;
            if (c0 < NN)
                k_edge_g<<<((c1e - c0) + 3) / 4, 256, 0, stream>>>(rowptr, dsts_s, ehs, Vb,
                                                                   btp, agg, c0, c1e);
        }
        float* dest = (s == NSTEPS - 1) ? (float*)d_out : nf;
        k_gru<<<(NN + 3) / 4, 256, 0, stream>>>(agg, cnt, hid, WihT, WhhT, bih, bhh, dest);
    }
}